// Round 12
// baseline (194.624 us; speedup 1.0000x reference)
//
#include <hip/hip_runtime.h>

// MHA forward: out = softmax(mask(QK^T/8)) V, with QKV/out projections.
// B=4, S=2048, D=1024, H=16, hd=64. fp32 in/out, bf16 MFMA compute.
// Mask [B,1,1,S] -> compact K/V to unmasked keys (~50%). Softmax scale
// folded into K projection. A converted to bf16 once (grid-stride cvt3),
// QKV GEMM: bf16 glds path, 3-buffer depth-2 counted-vmcnt pipeline.

#define SEQ   2048
#define EDIM  1024
#define NHEAD 16
#define HDIM  64
#define NBAT  4
#define MTOK  8192           // B*S

typedef __attribute__((ext_vector_type(8))) __bf16 bf16x8;
typedef __attribute__((ext_vector_type(4))) __bf16 bf16x4;
typedef __attribute__((ext_vector_type(4))) float f32x4;
typedef __attribute__((ext_vector_type(16))) float f32x16;
typedef __attribute__((ext_vector_type(8))) unsigned short us8;
typedef unsigned short u16;

// log2(e)/8 : folds the 1/sqrt(hd) scale and the exp->exp2 conversion
#define SCL   0.1803368801111244f

__device__ __forceinline__ u16 bfbits(float f) {
    __bf16 h = (__bf16)f;
    return __builtin_bit_cast(u16, h);
}
__device__ __forceinline__ bf16x8 bc(us8 v) { return __builtin_bit_cast(bf16x8, v); }
__device__ __forceinline__ float exp2fast(float x) {
    float r;
    asm("v_exp_f32 %0, %1" : "=v"(r) : "v"(x));
    return r;
}
// async global->LDS, 16B per lane; LDS dest = wave-uniform base + lane*16
__device__ __forceinline__ void glds16(const void* g, void* l) {
    __builtin_amdgcn_global_load_lds(
        (const __attribute__((address_space(1))) unsigned int*)g,
        (__attribute__((address_space(3))) unsigned int*)l, 16, 0, 0);
}
#define VMCNT(n) asm volatile("s_waitcnt vmcnt(" #n ")" ::: "memory")

// ---------------------------------------------------------------------------
// Kernel 0: per-batch compaction of the key mask.
// ---------------------------------------------------------------------------
__global__ __launch_bounds__(256) void prep_kernel(const int* __restrict__ mask,
                                                   int* __restrict__ idxl,
                                                   int* __restrict__ cntp) {
    __shared__ int psum[257];
    const int b = blockIdx.x, t = threadIdx.x;
    const int* mp = mask + b * SEQ;
    int m8[8]; int s = 0;
#pragma unroll
    for (int i = 0; i < 8; ++i) { m8[i] = mp[t * 8 + i]; s += (m8[i] != 0); }
    psum[t + 1] = s;
    __syncthreads();
    if (t == 0) { psum[0] = 0; for (int i = 1; i <= 256; ++i) psum[i] += psum[i - 1]; }
    __syncthreads();
    int ex = psum[t];
#pragma unroll
    for (int i = 0; i < 8; ++i)
        if (m8[i] != 0) idxl[b * SEQ + (ex++)] = t * 8 + i;
    if (t == 0) cntp[b] = psum[256];
}

// ---------------------------------------------------------------------------
// Kernel 1: 4x W [K,N] fp32 -> WT [N,K] bf16 (transpose + cast)
// ---------------------------------------------------------------------------
__global__ __launch_bounds__(256) void wtrans4_kernel(const float* __restrict__ W0,
                                                      const float* __restrict__ W1,
                                                      const float* __restrict__ W2,
                                                      const float* __restrict__ W3,
                                                      u16* __restrict__ WT) {
    __shared__ float tile[32][33];
    const int tx = threadIdx.x, ty = threadIdx.y;
    const int bx = blockIdx.x,  by = blockIdx.y, wz = blockIdx.z;
    const float* W = (wz == 0) ? W0 : (wz == 1) ? W1 : (wz == 2) ? W2 : W3;
    u16* O = WT + (size_t)wz * EDIM * EDIM;
#pragma unroll
    for (int i = 0; i < 4; ++i)
        tile[ty + i * 8][tx] = W[(size_t)(by * 32 + ty + i * 8) * EDIM + bx * 32 + tx];
    __syncthreads();
#pragma unroll
    for (int i = 0; i < 4; ++i) {
        int n = bx * 32 + ty + i * 8;
        int k = by * 32 + tx;
        O[(size_t)n * EDIM + k] = bfbits(tile[tx][ty + i * 8]);
    }
}

// ---------------------------------------------------------------------------
// Kernel 1b: grid-stride fp32 -> bf16 conversion of query/key/value.
// grid (1024, 3); 16 elems per thread-iteration, 2 iterations -> ILP.
// ---------------------------------------------------------------------------
__global__ __launch_bounds__(256) void cvt3_kernel(const float* __restrict__ q,
                                                   const float* __restrict__ k,
                                                   const float* __restrict__ v,
                                                   u16* __restrict__ oq,
                                                   u16* __restrict__ ok,
                                                   u16* __restrict__ ov) {
    const int sel = blockIdx.y;
    const float* a = (sel == 0) ? q : (sel == 1) ? k : v;
    u16* o = (sel == 0) ? oq : (sel == 1) ? ok : ov;
    const size_t N = (size_t)MTOK * EDIM;
    const size_t stride = (size_t)gridDim.x * 256 * 16;
    for (size_t i = ((size_t)blockIdx.x * 256 + threadIdx.x) * 16; i < N; i += stride) {
        f32x4 v0 = *(const f32x4*)(a + i);
        f32x4 v1 = *(const f32x4*)(a + i + 4);
        f32x4 v2 = *(const f32x4*)(a + i + 8);
        f32x4 v3 = *(const f32x4*)(a + i + 12);
        us8 r0, r1;
#pragma unroll
        for (int j = 0; j < 4; ++j) {
            r0[j] = bfbits(v0[j]); r0[4 + j] = bfbits(v1[j]);
            r1[j] = bfbits(v2[j]); r1[4 + j] = bfbits(v3[j]);
        }
        *(us8*)(o + i) = r0;
        *(us8*)(o + i + 8) = r1;
    }
}

// ---------------------------------------------------------------------------
// Kernel 2a: merged QKV projections, one 1536-block launch.
//   which = id>>9: 0=Q (no gather, [B,H,S,64]), 1=K (gather, scaled, same),
//                  2=V (gather, [B,H,64,S] transposed).
// ABF16=true: pre-converted bf16 A; 3-buffer depth-2, counted vmcnt(4),
// raw s_barrier (prefetch stays in flight). ABF16=false: fp32 fallback.
// ---------------------------------------------------------------------------
template <bool ABF16>
__global__ __launch_bounds__(256) void qkv_gemm_kernel(
        const void* __restrict__ Aq, const void* __restrict__ Ak,
        const void* __restrict__ Av, const u16* __restrict__ WTall,
        const float* __restrict__ bqp, const float* __restrict__ bkp,
        const float* __restrict__ bvp,
        u16* __restrict__ Qb, u16* __restrict__ Kb, u16* __restrict__ Vb,
        const int* __restrict__ idxl, const int* __restrict__ cntp) {
    const int id    = blockIdx.x;
    const int which = id >> 9;            // 0,1,2
    const int sub   = id & 511;
    const int r_    = sub >> 3;
    const int grp   = r_ >> 5, bnq = (r_ >> 2) & 7, bmin = r_ & 3;
    const int bm    = (sub & 7) + 8 * (grp * 4 + bmin);
    const int bn    = bnq;

    const void*  A    = (which == 0) ? Aq : (which == 1) ? Ak : Av;
    const u16*   WT   = WTall + (size_t)which * EDIM * EDIM;
    const float* bias = (which == 0) ? bqp : (which == 1) ? bkp : bvp;
    u16*         outp = (which == 0) ? Qb : (which == 1) ? Kb : Vb;
    const float  oscale = (which == 1) ? SCL : 1.0f;
    const bool   gather = (which > 0);

    int cn = SEQ;
    if (gather) {
        cn = cntp[bm >> 4];
        if (((bm & 15) * 128) >= cn) return;
    }

    __shared__ __align__(16) char Asraw[3][128 * 32 * (ABF16 ? 2 : 4)];
    __shared__ __align__(16) u16  Bs[3][128][32];

    const int tid  = threadIdx.x;
    const int lane = tid & 63, w = tid >> 6;
    const int g    = lane >> 4, l15 = lane & 15;
    const int wrow = w >> 1, wcol = w & 1;

    const char* pa[ABF16 ? 2 : 4];
    if constexpr (ABF16) {
        const u16* Ab = (const u16*)A;
#pragma unroll
        for (int t = 0; t < 2; ++t) {
            const int rloc = w * 32 + t * 16 + (lane >> 2);
            int arow;
            if (gather) {
                const int sloc = (bm & 15) * 128 + rloc;
                const int gi = (sloc < cn) ? idxl[(bm >> 4) * SEQ + sloc] : 0;
                arow = (bm >> 4) * SEQ + gi;
            } else arow = bm * 128 + rloc;
            const int scol = ((lane & 3) ^ ((lane >> 3) & 3)) * 8;
            pa[t] = (const char*)(Ab + (size_t)arow * EDIM + scol);
        }
    } else {
        const float* Af = (const float*)A;
#pragma unroll
        for (int t = 0; t < 4; ++t) {
            const int rloc = w * 32 + t * 8 + (lane >> 3);
            int arow;
            if (gather) {
                const int sloc = (bm & 15) * 128 + rloc;
                const int gi = (sloc < cn) ? idxl[(bm >> 4) * SEQ + sloc] : 0;
                arow = (bm >> 4) * SEQ + gi;
            } else arow = bm * 128 + rloc;
            const int scol = ((lane & 7) ^ (lane >> 3)) * 4;
            pa[t] = (const char*)(Af + (size_t)arow * EDIM + scol);
        }
    }
    const char* pb[2];
#pragma unroll
    for (int t = 0; t < 2; ++t) {
        const int rloc = w * 32 + t * 16 + (lane >> 2);
        const int brow = bn * 128 + rloc;
        const int scol = ((lane & 3) ^ ((lane >> 3) & 3)) * 8;
        pb[t] = (const char*)(WT + (size_t)brow * EDIM + scol);
    }

    auto STAGE = [&](int bufn, int ko) {
        char* abase = &Asraw[bufn][0] + w * (ABF16 ? 2048 : 4096);
        if constexpr (ABF16) {
#pragma unroll
            for (int t = 0; t < 2; ++t)
                glds16(pa[t] + (size_t)ko * 2, abase + t * 1024);
        } else {
#pragma unroll
            for (int t = 0; t < 4; ++t)
                glds16(pa[t] + (size_t)ko * 4, abase + t * 1024);
        }
        char* bbase = (char*)&Bs[bufn][0][0] + w * 2048;
#pragma unroll
        for (int t = 0; t < 2; ++t)
            glds16(pb[t] + (size_t)ko * 2, bbase + t * 1024);
    };

    f32x4 acc[4][4] = {};
    constexpr int NT = EDIM / 32;

    // depth-2 prologue: tiles 0 and 1 in flight; wait tile 0 only.
    STAGE(0, 0);
    STAGE(1, 32);
    if constexpr (ABF16) VMCNT(4); else VMCNT(6);
    __builtin_amdgcn_s_barrier();

    int bcur = 0, bn1 = 1, bn2 = 2;
#pragma unroll 1
    for (int kt = 0; kt < NT; ++kt) {
        if (kt + 2 < NT) STAGE(bn2, (kt + 2) * 32);

        bf16x8 af[4], bfr[4];
        if constexpr (ABF16) {
            const u16* As = (const u16*)&Asraw[bcur][0];
            const int x = (l15 >> 1) & 3;
#pragma unroll
            for (int i = 0; i < 4; ++i) {
                const int row = wrow * 64 + i * 16 + l15;
                af[i] = bc(*(const us8*)(As + row * 32 + ((g ^ x) * 8)));
            }
        } else {
            const float* As = (const float*)&Asraw[bcur][0];
            const int x = l15 & 7;
#pragma unroll
            for (int i = 0; i < 4; ++i) {
                const int row = wrow * 64 + i * 16 + l15;
                f32x4 u0 = *(const f32x4*)(As + row * 32 + (((2 * g)     ^ x) * 4));
                f32x4 u1 = *(const f32x4*)(As + row * 32 + (((2 * g + 1) ^ x) * 4));
#pragma unroll
                for (int j = 0; j < 4; ++j) {
                    af[i][j]     = (__bf16)u0[j];
                    af[i][4 + j] = (__bf16)u1[j];
                }
            }
        }
        {
            const int x = (l15 >> 1) & 3;
#pragma unroll
            for (int j = 0; j < 4; ++j) {
                const int row = wcol * 64 + j * 16 + l15;
                bfr[j] = bc(*(const us8*)((const u16*)&Bs[bcur][0][0] + row * 32 + ((g ^ x) * 8)));
            }
        }

#pragma unroll
        for (int i = 0; i < 4; ++i)
#pragma unroll
            for (int j = 0; j < 4; ++j)
                acc[i][j] = __builtin_amdgcn_mfma_f32_16x16x32_bf16(af[i], bfr[j], acc[i][j], 0, 0, 0);

        if (kt + 1 < NT) {
            if (kt + 2 < NT) {              // wait tile kt+1; kt+2 stays in flight
                if constexpr (ABF16) VMCNT(4); else VMCNT(6);
            } else {
                VMCNT(0);
            }
            __builtin_amdgcn_s_barrier();
        }
        const int t = bcur; bcur = bn1; bn1 = bn2; bn2 = t;
    }

    // epilogue: C/D layout: col = lane&15, row = (lane>>4)*4 + r
#pragma unroll
    for (int i = 0; i < 4; ++i) {
#pragma unroll
        for (int j = 0; j < 4; ++j) {
            const int gm0 = bm * 128 + wrow * 64 + i * 16 + g * 4;
            const int gn  = bn * 128 + wcol * 64 + j * 16 + l15;
            const float bv = bias[gn];
#pragma unroll
            for (int r = 0; r < 4; ++r) {
                float val = (acc[i][j][r] + bv) * oscale;
                const int m = gm0 + r;
                if (gather && (m & 2047) >= cn) val = 0.f;
                const int b = m >> 11, s = m & 2047;
                const int h = gn >> 6, d = gn & 63;
                if (which == 2)
                    outp[((size_t)(b * NHEAD + h) << 17) + d * SEQ + s] = bfbits(val);
                else
                    outp[((size_t)(b * NHEAD + h) << 17) + s * HDIM + d] = bfbits(val);
            }
        }
    }
}

// ---------------------------------------------------------------------------
// Kernel 2b: O-projection. C[M,N] fp32 = Abuf(bf16)[M,1024] * Wo + bo.
// Same depth-2 counted-vmcnt pipeline (4 loads per STAGE).
// ---------------------------------------------------------------------------
__global__ __launch_bounds__(256) void o_gemm_kernel(const u16* __restrict__ Ap,
                                                     const u16* __restrict__ WT,
                                                     const float* __restrict__ bias,
                                                     float* __restrict__ outp) {
    const int id  = blockIdx.x;
    const int r_  = id >> 3;
    const int grp = r_ >> 5, bnq = (r_ >> 2) & 7, bmin = r_ & 3;
    const int bm  = (id & 7) + 8 * (grp * 4 + bmin);
    const int bn  = bnq;

    __shared__ __align__(16) u16 As[3][128][32];
    __shared__ __align__(16) u16 Bs[3][128][32];

    const int tid  = threadIdx.x;
    const int lane = tid & 63, w = tid >> 6;
    const int g    = lane >> 4, l15 = lane & 15;
    const int wrow = w >> 1, wcol = w & 1;

    const char* pa[2]; const char* pb[2];
#pragma unroll
    for (int t = 0; t < 2; ++t) {
        const int rloc = w * 32 + t * 16 + (lane >> 2);
        const int scol = ((lane & 3) ^ ((lane >> 3) & 3)) * 8;
        pa[t] = (const char*)(Ap + (size_t)(bm * 128 + rloc) * EDIM + scol);
        pb[t] = (const char*)(WT + (size_t)(bn * 128 + rloc) * EDIM + scol);
    }

    auto STAGE = [&](int bufn, int ko) {
        char* abase = (char*)&As[bufn][0][0] + w * 2048;
        char* bbase = (char*)&Bs[bufn][0][0] + w * 2048;
#pragma unroll
        for (int t = 0; t < 2; ++t) {
            glds16(pa[t] + (size_t)ko * 2, abase + t * 1024);
            glds16(pb[t] + (size_t)ko * 2, bbase + t * 1024);
        }
    };

    f32x4 acc[4][4] = {};
    constexpr int NT = EDIM / 32;

    STAGE(0, 0);
    STAGE(1, 32);
    VMCNT(4);
    __builtin_amdgcn_s_barrier();

    int bcur = 0, bn1 = 1, bn2 = 2;
#pragma unroll 1
    for (int kt = 0; kt < NT; ++kt) {
        if (kt + 2 < NT) STAGE(bn2, (kt + 2) * 32);

        bf16x8 af[4], bfr[4];
        const int x = (l15 >> 1) & 3;
#pragma unroll
        for (int i = 0; i < 4; ++i) {
            const int rowA = wrow * 64 + i * 16 + l15;
            af[i] = bc(*(const us8*)((const u16*)&As[bcur][0][0] + rowA * 32 + ((g ^ x) * 8)));
            const int rowB = wcol * 64 + i * 16 + l15;
            bfr[i] = bc(*(const us8*)((const u16*)&Bs[bcur][0][0] + rowB * 32 + ((g ^ x) * 8)));
        }

#pragma unroll
        for (int i = 0; i < 4; ++i)
#pragma unroll
            for (int j = 0; j < 4; ++j)
                acc[i][j] = __builtin_amdgcn_mfma_f32_16x16x32_bf16(af[i], bfr[j], acc[i][j], 0, 0, 0);

        if (kt + 1 < NT) {
            if (kt + 2 < NT) { VMCNT(4); } else { VMCNT(0); }
            __builtin_amdgcn_s_barrier();
        }
        const int t = bcur; bcur = bn1; bn1 = bn2; bn2 = t;
    }

#pragma unroll
    for (int i = 0; i < 4; ++i) {
#pragma unroll
        for (int j = 0; j < 4; ++j) {
            const int gm0 = bm * 128 + wrow * 64 + i * 16 + g * 4;
            const int gn  = bn * 128 + wcol * 64 + j * 16 + l15;
            const float bv = bias[gn];
#pragma unroll
            for (int r = 0; r < 4; ++r)
                outp[(size_t)(gm0 + r) * EDIM + gn] = acc[i][j][r] + bv;
        }
    }
}

// ---------------------------------------------------------------------------
// Kernel 3: flash attention over COMPACTED keys, 32x32 MFMA, in-register P.
// (unchanged: fixed K swizzle f(r)=(r&3)|(((r>>3)&1)<<2), ones-MFMA rowsum)
// ---------------------------------------------------------------------------
__global__ __launch_bounds__(256) void attn_kernel(const u16* __restrict__ Q,
                                                   const u16* __restrict__ K,
                                                   const u16* __restrict__ VT,
                                                   const int* __restrict__ cntp,
                                                   u16* __restrict__ O) {
    __shared__ u16 Klds[2][64][64];
    __shared__ u16 Vlds[2][64][64];

    const int tid = threadIdx.x, lane = tid & 63, w = tid >> 6;
    const int h = lane >> 5, l31 = lane & 31;

    const int id  = blockIdx.x;             // 0..1023, XCD-aware mapping
    const int bh  = (id & 7) * 8 + ((id >> 3) >> 4);
    const int qb  = (id >> 3) & 15;
    const int b   = bh >> 4, hd_ = bh & 15;

    const u16* Qp = Q + ((size_t)bh << 17);
    const u16* Kp = K + ((size_t)bh << 17);
    const u16* Vp = VT + ((size_t)bh << 17);
    const int q0w = qb * 128 + w * 32;

    const int cn  = cntp[b];
    const int ktc = (cn + 63) >> 6;

    bf16x8 qf[4];
#pragma unroll
    for (int khd = 0; khd < 4; ++khd)
        qf[khd] = bc(*(const us8*)&Qp[(size_t)(q0w + l31) * HDIM + khd * 16 + h * 8]);

    const int b_  = l31 & 3, hp = (l31 >> 2) & 1, cc = l31 >> 3;
    const int piR = 16 * (cc & 1) + 8 * hp + 4 * (cc >> 1) + b_;
    const int swk = b_ | (hp << 2);
    const int swv = l31 & 7;

    const int lr = lane >> 3, lg = lane & 7;
    const u16* pKs[2]; const u16* pVs[2];
#pragma unroll
    for (int t = 0; t < 2; ++t) {
        const int rloc = w * 16 + t * 8 + lr;
        const int xk = (rloc & 3) | (((rloc >> 3) & 1) << 2);
        pKs[t] = Kp + (size_t)rloc * HDIM + ((lg ^ xk) << 3);
        const int xv = rloc & 7;
        pVs[t] = Vp + (size_t)rloc * SEQ + ((lg ^ xv) << 3);
    }

    auto STAGE = [&](int bufn, int kb) {
#pragma unroll
        for (int t = 0; t < 2; ++t) {
            glds16(pKs[t] + (size_t)kb * HDIM, &Klds[bufn][w * 16 + t * 8][0]);
            glds16(pVs[t] + kb,                &Vlds[bufn][w * 16 + t * 8][0]);
        }
    };

    f32x16 ot[2] = {};
    f32x16 ls = {};

    bf16x8 onesf;
#pragma unroll
    for (int j = 0; j < 8; ++j) onesf[j] = (__bf16)1.0f;

    STAGE(0, 0);
    __syncthreads();

    for (int kt = 0; kt < ktc; ++kt) {
        const int cur = kt & 1;
        const bool more = (kt + 1) < ktc;
        if (more) STAGE(cur ^ 1, (kt + 1) * 64);

        f32x16 st[2] = {};
        __builtin_amdgcn_s_setprio(1);
#pragma unroll
        for (int kb2 = 0; kb2 < 2; ++kb2) {
            const u16* Kr = &Klds[cur][kb2 * 32 + piR][0];
#pragma unroll
            for (int khd = 0; khd < 4; ++khd) {
                bf16x8 kf = bc(*(const us8*)&Kr[(khd * 16 + h * 8) ^ (swk << 3)]);
                st[kb2] = __builtin_amdgcn_mfma_f32_32x32x16_bf16(kf, qf[khd], st[kb2], 0, 0, 0);
            }
        }
        __builtin_amdgcn_s_setprio(0);

#pragma unroll
        for (int kb2 = 0; kb2 < 2; ++kb2)
#pragma unroll
            for (int e = 0; e < 16; ++e)
                st[kb2][e] = exp2fast(st[kb2][e]);

        if (kt == ktc - 1) {
            const int kbase = kt * 64;
#pragma unroll
            for (int kb2 = 0; kb2 < 2; ++kb2)
#pragma unroll
                for (int cp = 0; cp < 4; ++cp)
#pragma unroll
                    for (int j = 0; j < 4; ++j) {
                        const int key = kbase + kb2 * 32 + 16 * (cp & 1) + 4 * (cp >> 1) + 8 * h + j;
                        if (key >= cn) st[kb2][cp * 4 + j] = 0.f;
                    }
        }

        bf16x8 pf[4];
#pragma unroll
        for (int s = 0; s < 4; ++s) {
            const int kb2 = s >> 1, sel = (s & 1) * 4;
#pragma unroll
            for (int j = 0; j < 4; ++j) {
                pf[s][j]     = (__bf16)st[kb2][sel + j];
                pf[s][4 + j] = (__bf16)st[kb2][8 + sel + j];
            }
        }

        __builtin_amdgcn_s_setprio(1);
#pragma unroll
        for (int s = 0; s < 4; ++s)
            ls = __builtin_amdgcn_mfma_f32_32x32x16_bf16(onesf, pf[s], ls, 0, 0, 0);
#pragma unroll
        for (int dblk = 0; dblk < 2; ++dblk) {
            const u16* Vr = &Vlds[cur][dblk * 32 + l31][0];
#pragma unroll
            for (int s = 0; s < 4; ++s) {
                bf16x8 vf = bc(*(const us8*)&Vr[(s * 16 + h * 8) ^ (swv << 3)]);
                ot[dblk] = __builtin_amdgcn_mfma_f32_32x32x16_bf16(vf, pf[s], ot[dblk], 0, 0, 0);
            }
        }
        __builtin_amdgcn_s_setprio(0);

        __syncthreads();
    }

    const float inv = 1.f / ls[0];

    const size_t row = (size_t)(b * SEQ + q0w + l31) * EDIM + hd_ * HDIM;
#pragma unroll
    for (int dblk = 0; dblk < 2; ++dblk) {
#pragma unroll
        for (int cp = 0; cp < 4; ++cp) {
            bf16x4 t;
#pragma unroll
            for (int j = 0; j < 4; ++j)
                t[j] = (__bf16)(ot[dblk][cp * 4 + j] * inv);
            *(bf16x4*)&O[row + dblk * 32 + 8 * cp + 4 * h] = t;
        }
    }
}

// ---------------------------------------------------------------------------
extern "C" void kernel_launch(void* const* d_in, const int* in_sizes, int n_in,
                              void* d_out, int out_size, void* d_ws, size_t ws_size,
                              hipStream_t stream) {
    const float* query = (const float*)d_in[0];
    const float* key   = (const float*)d_in[1];
    const float* value = (const float*)d_in[2];
    const int*   mask  = (const int*)d_in[3];
    const float* Wq = (const float*)d_in[4];  const float* bq = (const float*)d_in[5];
    const float* Wk = (const float*)d_in[6];  const float* bk = (const float*)d_in[7];
    const float* Wv = (const float*)d_in[8];  const float* bv = (const float*)d_in[9];
    const float* Wo = (const float*)d_in[10]; const float* bo = (const float*)d_in[11];

    char* ws = (char*)d_ws;
    const size_t WT_BYTES  = (size_t)EDIM * EDIM * 2;      // 2 MiB
    const size_t BUF_BYTES = (size_t)MTOK * EDIM * 2;      // 16 MiB
    u16* wtq   = (u16*)(ws);                               // q,k,v,o contiguous
    u16* wto   = (u16*)(ws + 3 * WT_BYTES);
    u16* Qbuf  = (u16*)(ws + 4 * WT_BYTES);
    u16* Kbuf  = (u16*)(ws + 4 * WT_BYTES + BUF_BYTES);
    u16* VTbuf = (u16*)(ws + 4 * WT_BYTES + 2 * BUF_BYTES);
    char* X    = ws + 4 * WT_BYTES + 3 * BUF_BYTES;        // Abf region / Abuf
    u16* Abuf  = (u16*)X;

    const size_t need_big = 4 * WT_BYTES + 6 * BUF_BYTES + (size_t)MTOK * 4 + 64;
    const bool big = (ws_size >= need_big);
    u16* Abfq = (u16*)X;
    u16* Abfk = (u16*)(X + BUF_BYTES);
    u16* Abfv = (u16*)(X + 2 * BUF_BYTES);
    char* tail = big ? (X + 3 * BUF_BYTES) : (X + BUF_BYTES);
    int* idxl  = (int*)tail;
    int* cntp  = (int*)(tail + (size_t)MTOK * 4);

    prep_kernel<<<NBAT, 256, 0, stream>>>(mask, idxl, cntp);

    dim3 tgrid(32, 32, 4), tblk(32, 8);
    wtrans4_kernel<<<tgrid, tblk, 0, stream>>>(Wq, Wk, Wv, Wo, wtq);

    if (big) {
        cvt3_kernel<<<dim3(1024, 3), 256, 0, stream>>>(query, key, value,
                                                       Abfq, Abfk, Abfv);
        qkv_gemm_kernel<true><<<1536, 256, 0, stream>>>(Abfq, Abfk, Abfv, wtq,
                                                        bq, bk, bv,
                                                        Qbuf, Kbuf, VTbuf,
                                                        idxl, cntp);
    } else {
        qkv_gemm_kernel<false><<<1536, 256, 0, stream>>>(query, key, value, wtq,
                                                         bq, bk, bv,
                                                         Qbuf, Kbuf, VTbuf,
                                                         idxl, cntp);
    }

    attn_kernel<<<1024, 256, 0, stream>>>(Qbuf, Kbuf, VTbuf, cntp, Abuf);

    o_gemm_kernel<<<512, 256, 0, stream>>>(Abuf, wto, bo, (float*)d_out);
}

// Round 13
// 182.737 us; speedup vs baseline: 1.0651x; 1.0651x over previous
//
#include <hip/hip_runtime.h>

// MHA forward: out = softmax(mask(QK^T/8)) V, with QKV/out projections.
// B=4, S=2048, D=1024, H=16, hd=64. fp32 in/out, bf16 MFMA compute.
// Mask [B,1,1,S] -> compact K/V to unmasked keys (~50%). Softmax scale
// folded into K projection. cvtg: one fused pass converts Q to bf16 and
// converts+gathers K/V into compacted row order (zero-padded to 128).
// All GEMMs run the proven 2-buffer bf16 glds path (32KB LDS).

#define SEQ   2048
#define EDIM  1024
#define NHEAD 16
#define HDIM  64
#define NBAT  4
#define MTOK  8192           // B*S

typedef __attribute__((ext_vector_type(8))) __bf16 bf16x8;
typedef __attribute__((ext_vector_type(4))) __bf16 bf16x4;
typedef __attribute__((ext_vector_type(4))) float f32x4;
typedef __attribute__((ext_vector_type(16))) float f32x16;
typedef __attribute__((ext_vector_type(8))) unsigned short us8;
typedef unsigned short u16;

// log2(e)/8 : folds the 1/sqrt(hd) scale and the exp->exp2 conversion
#define SCL   0.1803368801111244f

__device__ __forceinline__ u16 bfbits(float f) {
    __bf16 h = (__bf16)f;
    return __builtin_bit_cast(u16, h);
}
__device__ __forceinline__ bf16x8 bc(us8 v) { return __builtin_bit_cast(bf16x8, v); }
__device__ __forceinline__ float exp2fast(float x) {
    float r;
    asm("v_exp_f32 %0, %1" : "=v"(r) : "v"(x));
    return r;
}
// async global->LDS, 16B per lane; LDS dest = wave-uniform base + lane*16
__device__ __forceinline__ void glds16(const void* g, void* l) {
    __builtin_amdgcn_global_load_lds(
        (const __attribute__((address_space(1))) unsigned int*)g,
        (__attribute__((address_space(3))) unsigned int*)l, 16, 0, 0);
}

// ---------------------------------------------------------------------------
// Kernel 0: per-batch compaction of the key mask.
// ---------------------------------------------------------------------------
__global__ __launch_bounds__(256) void prep_kernel(const int* __restrict__ mask,
                                                   int* __restrict__ idxl,
                                                   int* __restrict__ cntp) {
    __shared__ int psum[257];
    const int b = blockIdx.x, t = threadIdx.x;
    const int* mp = mask + b * SEQ;
    int m8[8]; int s = 0;
#pragma unroll
    for (int i = 0; i < 8; ++i) { m8[i] = mp[t * 8 + i]; s += (m8[i] != 0); }
    psum[t + 1] = s;
    __syncthreads();
    if (t == 0) { psum[0] = 0; for (int i = 1; i <= 256; ++i) psum[i] += psum[i - 1]; }
    __syncthreads();
    int ex = psum[t];
#pragma unroll
    for (int i = 0; i < 8; ++i)
        if (m8[i] != 0) idxl[b * SEQ + (ex++)] = t * 8 + i;
    if (t == 0) cntp[b] = psum[256];
}

// ---------------------------------------------------------------------------
// Kernel 1: 4x W [K,N] fp32 -> WT [N,K] bf16 (transpose + cast)
// ---------------------------------------------------------------------------
__global__ __launch_bounds__(256) void wtrans4_kernel(const float* __restrict__ W0,
                                                      const float* __restrict__ W1,
                                                      const float* __restrict__ W2,
                                                      const float* __restrict__ W3,
                                                      u16* __restrict__ WT) {
    __shared__ float tile[32][33];
    const int tx = threadIdx.x, ty = threadIdx.y;
    const int bx = blockIdx.x,  by = blockIdx.y, wz = blockIdx.z;
    const float* W = (wz == 0) ? W0 : (wz == 1) ? W1 : (wz == 2) ? W2 : W3;
    u16* O = WT + (size_t)wz * EDIM * EDIM;
#pragma unroll
    for (int i = 0; i < 4; ++i)
        tile[ty + i * 8][tx] = W[(size_t)(by * 32 + ty + i * 8) * EDIM + bx * 32 + tx];
    __syncthreads();
#pragma unroll
    for (int i = 0; i < 4; ++i) {
        int n = bx * 32 + ty + i * 8;
        int k = by * 32 + tx;
        O[(size_t)n * EDIM + k] = bfbits(tile[tx][ty + i * 8]);
    }
}

// ---------------------------------------------------------------------------
// Kernel 1b: fused fp32->bf16 convert (+gather for K/V).
// grid (2048, 3): 4 rows per block (64 lanes x 16 elems each).
//   sel 0: Q straight convert.
//   sel 1/2: K/V -> compacted row order via idxl; rows [cn, ceil128(cn))
//            zero-filled; rows beyond that never read by the GEMM.
// ---------------------------------------------------------------------------
__global__ __launch_bounds__(256) void cvtg_kernel(const float* __restrict__ q,
                                                   const float* __restrict__ k,
                                                   const float* __restrict__ v,
                                                   const int* __restrict__ idxl,
                                                   const int* __restrict__ cntp,
                                                   u16* __restrict__ oq,
                                                   u16* __restrict__ ok,
                                                   u16* __restrict__ ov) {
    const int sel  = blockIdx.y;
    const int grow = blockIdx.x * 4 + (threadIdx.x >> 6);   // 0..8191
    const int col  = (threadIdx.x & 63) * 16;
    const float* src;
    u16* dst;
    if (sel == 0) {
        src = q + (size_t)grow * EDIM;
        dst = oq + (size_t)grow * EDIM;
    } else {
        const int b = grow >> 11, j = grow & 2047;
        const int cn = cntp[b];
        dst = (sel == 1 ? ok : ov) + (size_t)grow * EDIM;
        if (j < cn) {
            const int gi = idxl[b * SEQ + j];
            src = (sel == 1 ? k : v) + ((size_t)(b * SEQ + gi)) * EDIM;
        } else {
            if (j < ((cn + 127) & ~127)) {          // zero-pad partial block
                us8 z = {};
                *(us8*)(dst + col) = z;
                *(us8*)(dst + col + 8) = z;
            }
            return;
        }
    }
    f32x4 v0 = *(const f32x4*)(src + col);
    f32x4 v1 = *(const f32x4*)(src + col + 4);
    f32x4 v2 = *(const f32x4*)(src + col + 8);
    f32x4 v3 = *(const f32x4*)(src + col + 12);
    us8 r0, r1;
#pragma unroll
    for (int j2 = 0; j2 < 4; ++j2) {
        r0[j2] = bfbits(v0[j2]); r0[4 + j2] = bfbits(v1[j2]);
        r1[j2] = bfbits(v2[j2]); r1[4 + j2] = bfbits(v3[j2]);
    }
    *(us8*)(dst + col) = r0;
    *(us8*)(dst + col + 8) = r1;
}

// ---------------------------------------------------------------------------
// Kernel 2a: merged QKV projections, one 1536-block launch.
//   which = id>>9: 0=Q -> [B,H,S,64]; 1=K (scaled) -> [B,H,S,64];
//                  2=V -> [B,H,64,S] transposed.
// A: pre-converted (and pre-gathered for K/V) bf16, contiguous rows.
// 2-buffer glds pipeline, 32KB LDS, 1 barrier per K-step (R10-measured-best).
// ---------------------------------------------------------------------------
__global__ __launch_bounds__(256) void qkv_gemm_kernel(
        const u16* __restrict__ Aq, const u16* __restrict__ Ak,
        const u16* __restrict__ Av, const u16* __restrict__ WTall,
        const float* __restrict__ bqp, const float* __restrict__ bkp,
        const float* __restrict__ bvp,
        u16* __restrict__ Qb, u16* __restrict__ Kb, u16* __restrict__ Vb,
        const int* __restrict__ cntp) {
    const int id    = blockIdx.x;
    const int which = id >> 9;            // 0,1,2
    const int sub   = id & 511;
    const int r_    = sub >> 3;
    const int grp   = r_ >> 5, bnq = (r_ >> 2) & 7, bmin = r_ & 3;
    const int bm    = (sub & 7) + 8 * (grp * 4 + bmin);
    const int bn    = bnq;

    const u16*   A    = (which == 0) ? Aq : (which == 1) ? Ak : Av;
    const u16*   WT   = WTall + (size_t)which * EDIM * EDIM;
    const float* bias = (which == 0) ? bqp : (which == 1) ? bkp : bvp;
    u16*         outp = (which == 0) ? Qb : (which == 1) ? Kb : Vb;
    const float  oscale = (which == 1) ? SCL : 1.0f;

    int cn = SEQ;
    if (which > 0) {
        cn = cntp[bm >> 4];
        if (((bm & 15) * 128) >= cn) return;   // fully-padded block
    }

    __shared__ __align__(16) u16 As[2][128][32];
    __shared__ __align__(16) u16 Bs[2][128][32];

    const int tid  = threadIdx.x;
    const int lane = tid & 63, w = tid >> 6;
    const int g    = lane >> 4, l15 = lane & 15;
    const int wrow = w >> 1, wcol = w & 1;

    const char* pa[2]; const char* pb[2];
#pragma unroll
    for (int t = 0; t < 2; ++t) {
        const int rloc = w * 32 + t * 16 + (lane >> 2);
        const int scol = ((lane & 3) ^ ((lane >> 3) & 3)) * 8;
        pa[t] = (const char*)(A + (size_t)(bm * 128 + rloc) * EDIM + scol);
        pb[t] = (const char*)(WT + (size_t)(bn * 128 + rloc) * EDIM + scol);
    }

    auto STAGE = [&](int bufn, int ko) {
        char* abase = (char*)&As[bufn][0][0] + w * 2048;
        char* bbase = (char*)&Bs[bufn][0][0] + w * 2048;
#pragma unroll
        for (int t = 0; t < 2; ++t) {
            glds16(pa[t] + (size_t)ko * 2, abase + t * 1024);
            glds16(pb[t] + (size_t)ko * 2, bbase + t * 1024);
        }
    };

    f32x4 acc[4][4] = {};
    constexpr int NT = EDIM / 32;

    STAGE(0, 0);
    __syncthreads();

    int buf = 0;
#pragma unroll 1
    for (int kt = 0; kt < NT; ++kt) {
        if (kt < NT - 1) STAGE(buf ^ 1, (kt + 1) * 32);

        bf16x8 af[4], bfr[4];
        const int x = (l15 >> 1) & 3;
#pragma unroll
        for (int i = 0; i < 4; ++i) {
            const int rowA = wrow * 64 + i * 16 + l15;
            af[i] = bc(*(const us8*)((const u16*)&As[buf][0][0] + rowA * 32 + ((g ^ x) * 8)));
            const int rowB = wcol * 64 + i * 16 + l15;
            bfr[i] = bc(*(const us8*)((const u16*)&Bs[buf][0][0] + rowB * 32 + ((g ^ x) * 8)));
        }

#pragma unroll
        for (int i = 0; i < 4; ++i)
#pragma unroll
            for (int j = 0; j < 4; ++j)
                acc[i][j] = __builtin_amdgcn_mfma_f32_16x16x32_bf16(af[i], bfr[j], acc[i][j], 0, 0, 0);

        __syncthreads();
        buf ^= 1;
    }

    // epilogue: C/D layout: col = lane&15, row = (lane>>4)*4 + r
#pragma unroll
    for (int i = 0; i < 4; ++i) {
#pragma unroll
        for (int j = 0; j < 4; ++j) {
            const int gm0 = bm * 128 + wrow * 64 + i * 16 + g * 4;
            const int gn  = bn * 128 + wcol * 64 + j * 16 + l15;
            const float bv = bias[gn];
#pragma unroll
            for (int r = 0; r < 4; ++r) {
                float val = (acc[i][j][r] + bv) * oscale;
                const int m = gm0 + r;
                if (which > 0 && (m & 2047) >= cn) val = 0.f;
                const int b = m >> 11, s = m & 2047;
                const int h = gn >> 6, d = gn & 63;
                if (which == 2)
                    outp[((size_t)(b * NHEAD + h) << 17) + d * SEQ + s] = bfbits(val);
                else
                    outp[((size_t)(b * NHEAD + h) << 17) + s * HDIM + d] = bfbits(val);
            }
        }
    }
}

// ---------------------------------------------------------------------------
// Kernel 2b: O-projection. C[M,N] fp32 = Abuf(bf16)[M,1024] * Wo + bo.
// ---------------------------------------------------------------------------
__global__ __launch_bounds__(256) void o_gemm_kernel(const u16* __restrict__ Ap,
                                                     const u16* __restrict__ WT,
                                                     const float* __restrict__ bias,
                                                     float* __restrict__ outp) {
    const int id  = blockIdx.x;
    const int r_  = id >> 3;
    const int grp = r_ >> 5, bnq = (r_ >> 2) & 7, bmin = r_ & 3;
    const int bm  = (id & 7) + 8 * (grp * 4 + bmin);
    const int bn  = bnq;

    __shared__ __align__(16) u16 As[2][128][32];
    __shared__ __align__(16) u16 Bs[2][128][32];

    const int tid  = threadIdx.x;
    const int lane = tid & 63, w = tid >> 6;
    const int g    = lane >> 4, l15 = lane & 15;
    const int wrow = w >> 1, wcol = w & 1;

    const char* pa[2]; const char* pb[2];
#pragma unroll
    for (int t = 0; t < 2; ++t) {
        const int rloc = w * 32 + t * 16 + (lane >> 2);
        const int scol = ((lane & 3) ^ ((lane >> 3) & 3)) * 8;
        pa[t] = (const char*)(Ap + (size_t)(bm * 128 + rloc) * EDIM + scol);
        pb[t] = (const char*)(WT + (size_t)(bn * 128 + rloc) * EDIM + scol);
    }

    auto STAGE = [&](int bufn, int ko) {
        char* abase = (char*)&As[bufn][0][0] + w * 2048;
        char* bbase = (char*)&Bs[bufn][0][0] + w * 2048;
#pragma unroll
        for (int t = 0; t < 2; ++t) {
            glds16(pa[t] + (size_t)ko * 2, abase + t * 1024);
            glds16(pb[t] + (size_t)ko * 2, bbase + t * 1024);
        }
    };

    f32x4 acc[4][4] = {};
    constexpr int NT = EDIM / 32;

    STAGE(0, 0);
    __syncthreads();

    int buf = 0;
#pragma unroll 1
    for (int kt = 0; kt < NT; ++kt) {
        if (kt < NT - 1) STAGE(buf ^ 1, (kt + 1) * 32);

        bf16x8 af[4], bfr[4];
        const int x = (l15 >> 1) & 3;
#pragma unroll
        for (int i = 0; i < 4; ++i) {
            const int rowA = wrow * 64 + i * 16 + l15;
            af[i] = bc(*(const us8*)((const u16*)&As[buf][0][0] + rowA * 32 + ((g ^ x) * 8)));
            const int rowB = wcol * 64 + i * 16 + l15;
            bfr[i] = bc(*(const us8*)((const u16*)&Bs[buf][0][0] + rowB * 32 + ((g ^ x) * 8)));
        }

#pragma unroll
        for (int i = 0; i < 4; ++i)
#pragma unroll
            for (int j = 0; j < 4; ++j)
                acc[i][j] = __builtin_amdgcn_mfma_f32_16x16x32_bf16(af[i], bfr[j], acc[i][j], 0, 0, 0);

        __syncthreads();
        buf ^= 1;
    }

#pragma unroll
    for (int i = 0; i < 4; ++i) {
#pragma unroll
        for (int j = 0; j < 4; ++j) {
            const int gm0 = bm * 128 + wrow * 64 + i * 16 + g * 4;
            const int gn  = bn * 128 + wcol * 64 + j * 16 + l15;
            const float bv = bias[gn];
#pragma unroll
            for (int r = 0; r < 4; ++r)
                outp[(size_t)(gm0 + r) * EDIM + gn] = acc[i][j][r] + bv;
        }
    }
}

// ---------------------------------------------------------------------------
// Kernel 3: flash attention over COMPACTED keys, 32x32 MFMA, in-register P.
// (unchanged: K swizzle f(r)=(r&3)|(((r>>3)&1)<<2), ones-MFMA rowsum)
// ---------------------------------------------------------------------------
__global__ __launch_bounds__(256) void attn_kernel(const u16* __restrict__ Q,
                                                   const u16* __restrict__ K,
                                                   const u16* __restrict__ VT,
                                                   const int* __restrict__ cntp,
                                                   u16* __restrict__ O) {
    __shared__ u16 Klds[2][64][64];
    __shared__ u16 Vlds[2][64][64];

    const int tid = threadIdx.x, lane = tid & 63, w = tid >> 6;
    const int h = lane >> 5, l31 = lane & 31;

    const int id  = blockIdx.x;             // 0..1023, XCD-aware mapping
    const int bh  = (id & 7) * 8 + ((id >> 3) >> 4);
    const int qb  = (id >> 3) & 15;
    const int b   = bh >> 4, hd_ = bh & 15;

    const u16* Qp = Q + ((size_t)bh << 17);
    const u16* Kp = K + ((size_t)bh << 17);
    const u16* Vp = VT + ((size_t)bh << 17);
    const int q0w = qb * 128 + w * 32;

    const int cn  = cntp[b];
    const int ktc = (cn + 63) >> 6;

    bf16x8 qf[4];
#pragma unroll
    for (int khd = 0; khd < 4; ++khd)
        qf[khd] = bc(*(const us8*)&Qp[(size_t)(q0w + l31) * HDIM + khd * 16 + h * 8]);

    const int b_  = l31 & 3, hp = (l31 >> 2) & 1, cc = l31 >> 3;
    const int piR = 16 * (cc & 1) + 8 * hp + 4 * (cc >> 1) + b_;
    const int swk = b_ | (hp << 2);
    const int swv = l31 & 7;

    const int lr = lane >> 3, lg = lane & 7;
    const u16* pKs[2]; const u16* pVs[2];
#pragma unroll
    for (int t = 0; t < 2; ++t) {
        const int rloc = w * 16 + t * 8 + lr;
        const int xk = (rloc & 3) | (((rloc >> 3) & 1) << 2);
        pKs[t] = Kp + (size_t)rloc * HDIM + ((lg ^ xk) << 3);
        const int xv = rloc & 7;
        pVs[t] = Vp + (size_t)rloc * SEQ + ((lg ^ xv) << 3);
    }

    auto STAGE = [&](int bufn, int kb) {
#pragma unroll
        for (int t = 0; t < 2; ++t) {
            glds16(pKs[t] + (size_t)kb * HDIM, &Klds[bufn][w * 16 + t * 8][0]);
            glds16(pVs[t] + kb,                &Vlds[bufn][w * 16 + t * 8][0]);
        }
    };

    f32x16 ot[2] = {};
    f32x16 ls = {};

    bf16x8 onesf;
#pragma unroll
    for (int j = 0; j < 8; ++j) onesf[j] = (__bf16)1.0f;

    STAGE(0, 0);
    __syncthreads();

    for (int kt = 0; kt < ktc; ++kt) {
        const int cur = kt & 1;
        const bool more = (kt + 1) < ktc;
        if (more) STAGE(cur ^ 1, (kt + 1) * 64);

        f32x16 st[2] = {};
        __builtin_amdgcn_s_setprio(1);
#pragma unroll
        for (int kb2 = 0; kb2 < 2; ++kb2) {
            const u16* Kr = &Klds[cur][kb2 * 32 + piR][0];
#pragma unroll
            for (int khd = 0; khd < 4; ++khd) {
                bf16x8 kf = bc(*(const us8*)&Kr[(khd * 16 + h * 8) ^ (swk << 3)]);
                st[kb2] = __builtin_amdgcn_mfma_f32_32x32x16_bf16(kf, qf[khd], st[kb2], 0, 0, 0);
            }
        }
        __builtin_amdgcn_s_setprio(0);

#pragma unroll
        for (int kb2 = 0; kb2 < 2; ++kb2)
#pragma unroll
            for (int e = 0; e < 16; ++e)
                st[kb2][e] = exp2fast(st[kb2][e]);

        if (kt == ktc - 1) {
            const int kbase = kt * 64;
#pragma unroll
            for (int kb2 = 0; kb2 < 2; ++kb2)
#pragma unroll
                for (int cp = 0; cp < 4; ++cp)
#pragma unroll
                    for (int j = 0; j < 4; ++j) {
                        const int key = kbase + kb2 * 32 + 16 * (cp & 1) + 4 * (cp >> 1) + 8 * h + j;
                        if (key >= cn) st[kb2][cp * 4 + j] = 0.f;
                    }
        }

        bf16x8 pf[4];
#pragma unroll
        for (int s = 0; s < 4; ++s) {
            const int kb2 = s >> 1, sel = (s & 1) * 4;
#pragma unroll
            for (int j = 0; j < 4; ++j) {
                pf[s][j]     = (__bf16)st[kb2][sel + j];
                pf[s][4 + j] = (__bf16)st[kb2][8 + sel + j];
            }
        }

        __builtin_amdgcn_s_setprio(1);
#pragma unroll
        for (int s = 0; s < 4; ++s)
            ls = __builtin_amdgcn_mfma_f32_32x32x16_bf16(onesf, pf[s], ls, 0, 0, 0);
#pragma unroll
        for (int dblk = 0; dblk < 2; ++dblk) {
            const u16* Vr = &Vlds[cur][dblk * 32 + l31][0];
#pragma unroll
            for (int s = 0; s < 4; ++s) {
                bf16x8 vf = bc(*(const us8*)&Vr[(s * 16 + h * 8) ^ (swv << 3)]);
                ot[dblk] = __builtin_amdgcn_mfma_f32_32x32x16_bf16(vf, pf[s], ot[dblk], 0, 0, 0);
            }
        }
        __builtin_amdgcn_s_setprio(0);

        __syncthreads();
    }

    const float inv = 1.f / ls[0];

    const size_t row = (size_t)(b * SEQ + q0w + l31) * EDIM + hd_ * HDIM;
#pragma unroll
    for (int dblk = 0; dblk < 2; ++dblk) {
#pragma unroll
        for (int cp = 0; cp < 4; ++cp) {
            bf16x4 t;
#pragma unroll
            for (int j = 0; j < 4; ++j)
                t[j] = (__bf16)(ot[dblk][cp * 4 + j] * inv);
            *(bf16x4*)&O[row + dblk * 32 + 8 * cp + 4 * h] = t;
        }
    }
}

// ---------------------------------------------------------------------------
extern "C" void kernel_launch(void* const* d_in, const int* in_sizes, int n_in,
                              void* d_out, int out_size, void* d_ws, size_t ws_size,
                              hipStream_t stream) {
    const float* query = (const float*)d_in[0];
    const float* key   = (const float*)d_in[1];
    const float* value = (const float*)d_in[2];
    const int*   mask  = (const int*)d_in[3];
    const float* Wq = (const float*)d_in[4];  const float* bq = (const float*)d_in[5];
    const float* Wk = (const float*)d_in[6];  const float* bk = (const float*)d_in[7];
    const float* Wv = (const float*)d_in[8];  const float* bv = (const float*)d_in[9];
    const float* Wo = (const float*)d_in[10]; const float* bo = (const float*)d_in[11];

    char* ws = (char*)d_ws;
    const size_t WT_BYTES  = (size_t)EDIM * EDIM * 2;      // 2 MiB
    const size_t BUF_BYTES = (size_t)MTOK * EDIM * 2;      // 16 MiB
    u16* wtq   = (u16*)(ws);                               // q,k,v,o contiguous
    u16* wto   = (u16*)(ws + 3 * WT_BYTES);
    u16* Qbuf  = (u16*)(ws + 4 * WT_BYTES);
    u16* Kbuf  = (u16*)(ws + 4 * WT_BYTES + BUF_BYTES);
    u16* VTbuf = (u16*)(ws + 4 * WT_BYTES + 2 * BUF_BYTES);
    char* X    = ws + 4 * WT_BYTES + 3 * BUF_BYTES;
    // X region: bf16 A copies (Qbf | Kc | Vc, 48 MiB); Abuf overlays Qbf
    // after qkv_gemm has consumed it (same verified footprint as before).
    u16* Qbf   = (u16*)X;
    u16* Kc    = (u16*)(X + BUF_BYTES);
    u16* Vc    = (u16*)(X + 2 * BUF_BYTES);
    u16* Abuf  = (u16*)X;
    int* idxl  = (int*)(X + 3 * BUF_BYTES);
    int* cntp  = (int*)(X + 3 * BUF_BYTES + (size_t)MTOK * 4);

    prep_kernel<<<NBAT, 256, 0, stream>>>(mask, idxl, cntp);

    dim3 tgrid(32, 32, 4), tblk(32, 8);
    wtrans4_kernel<<<tgrid, tblk, 0, stream>>>(Wq, Wk, Wv, Wo, wtq);

    cvtg_kernel<<<dim3(2048, 3), 256, 0, stream>>>(query, key, value,
                                                   idxl, cntp, Qbf, Kc, Vc);

    qkv_gemm_kernel<<<1536, 256, 0, stream>>>(Qbf, Kc, Vc, wtq,
                                              bq, bk, bv, Qbuf, Kbuf, VTbuf,
                                              cntp);

    attn_kernel<<<1024, 256, 0, stream>>>(Qbuf, Kbuf, VTbuf, cntp, Abuf);

    o_gemm_kernel<<<512, 256, 0, stream>>>(Abuf, wto, bo, (float*)d_out);
}